// Round 1
// baseline (219.973 us; speedup 1.0000x reference)
//
#include <hip/hip_runtime.h>

// AFM: B=4096, F=50 fields, D=16, A=32 attention dim, P=1225 pairs.
// out[b] = sum_p softmax_p( relu(inter_p @ W) . h ) * (inter_p . p_vec)
// where inter_p = e_i * e_j elementwise, (i,j) = triu_indices(F, k=1).

#define FF 50
#define DD 16
#define AA 32
#define NP 1225   // FF*(FF-1)/2

__global__ __launch_bounds__(256) void afm_kernel(
    const float* __restrict__ feat,   // [B, 50, 16]
    const float* __restrict__ W,      // [16, 32]
    const float* __restrict__ h,      // [32]
    const float* __restrict__ pvec,   // [16]
    float* __restrict__ out)          // [B]
{
  __shared__ float e[FF * DD];           // 800 floats, rows 64B aligned
  __shared__ unsigned int table[NP];     // (i<<8)|j
  __shared__ float s_lds[NP];
  __shared__ float g_lds[NP];
  __shared__ float red[8];
  __shared__ float red2[8][2];

  const int tid = threadIdx.x;
  const int b = blockIdx.x;

  // ---- stage this batch element's embeddings (200 float4 = 3.2 KB) ----
  const float4* src4 = reinterpret_cast<const float4*>(feat + (size_t)b * (FF * DD));
  float4* e4 = reinterpret_cast<float4*>(e);
  if (tid < 200) e4[tid] = src4[tid];

  // ---- build triu pair table (thread i fills row i's pairs) ----
  if (tid < FF - 1) {
    int i = tid;
    int off = i * (FF - 1) - (i * (i - 1)) / 2;
    for (int n = 0; n < FF - 1 - i; ++n)
      table[off + n] = ((unsigned)i << 8) | (unsigned)(i + 1 + n);
  }

  // ---- per-lane weight columns: lane l owns output cols l and l+16 ----
  const int l = tid & 15;
  float wlo[DD], whi[DD], pv[DD];
  #pragma unroll
  for (int d = 0; d < DD; ++d) {
    wlo[d] = W[d * AA + l];
    whi[d] = W[d * AA + l + 16];
    pv[d]  = pvec[d];
  }
  const float ha = h[l], hb = h[l + 16];

  __syncthreads();

  // ---- phase 1: per-pair scores + g, 16 groups of 16 lanes ----
  const int grp = tid >> 4;
  for (int p = grp; p < NP; p += 16) {
    unsigned pk = table[p];            // group-uniform LDS broadcast
    int i = (int)(pk >> 8), j = (int)(pk & 255u);
    const float4* ei4 = reinterpret_cast<const float4*>(e + i * DD);
    const float4* ej4 = reinterpret_cast<const float4*>(e + j * DD);
    float inter[DD];
    #pragma unroll
    for (int q = 0; q < 4; ++q) {
      float4 a4 = ei4[q], b4 = ej4[q];
      inter[q * 4 + 0] = a4.x * b4.x;
      inter[q * 4 + 1] = a4.y * b4.y;
      inter[q * 4 + 2] = a4.z * b4.z;
      inter[q * 4 + 3] = a4.w * b4.w;
    }
    float z0 = 0.f, z1 = 0.f, g = 0.f;
    #pragma unroll
    for (int d = 0; d < DD; ++d) {
      z0 = fmaf(inter[d], wlo[d], z0);
      z1 = fmaf(inter[d], whi[d], z1);
      g  = fmaf(inter[d], pv[d],  g);
    }
    float v = fmaxf(z0, 0.f) * ha + fmaxf(z1, 0.f) * hb;
    v += __shfl_xor(v, 1, 16);
    v += __shfl_xor(v, 2, 16);
    v += __shfl_xor(v, 4, 16);
    v += __shfl_xor(v, 8, 16);
    if (l == 0) { s_lds[p] = v; g_lds[p] = g; }
  }
  __syncthreads();

  // ---- phase 2: softmax over 1225 pairs + weighted sum of g ----
  float m = -3.4e38f;
  for (int p = tid; p < NP; p += 256) m = fmaxf(m, s_lds[p]);
  #pragma unroll
  for (int s = 32; s >= 1; s >>= 1) m = fmaxf(m, __shfl_xor(m, s, 64));
  const int wv = tid >> 6;
  if ((tid & 63) == 0) red[wv] = m;
  __syncthreads();
  m = fmaxf(fmaxf(red[0], red[1]), fmaxf(red[2], red[3]));

  float num = 0.f, den = 0.f;
  for (int p = tid; p < NP; p += 256) {
    float ex = __expf(s_lds[p] - m);
    den += ex;
    num = fmaf(ex, g_lds[p], num);
  }
  #pragma unroll
  for (int s = 32; s >= 1; s >>= 1) {
    num += __shfl_xor(num, s, 64);
    den += __shfl_xor(den, s, 64);
  }
  if ((tid & 63) == 0) { red2[wv][0] = num; red2[wv][1] = den; }
  __syncthreads();
  if (tid == 0) {
    float n  = red2[0][0] + red2[1][0] + red2[2][0] + red2[3][0];
    float dd = red2[0][1] + red2[1][1] + red2[2][1] + red2[3][1];
    out[b] = n / dd;
  }
}

extern "C" void kernel_launch(void* const* d_in, const int* in_sizes, int n_in,
                              void* d_out, int out_size, void* d_ws, size_t ws_size,
                              hipStream_t stream) {
  const float* feat = (const float*)d_in[0];
  const float* W    = (const float*)d_in[1];
  const float* h    = (const float*)d_in[2];
  const float* pvec = (const float*)d_in[3];
  float* out = (float*)d_out;
  const int B = in_sizes[0] / (FF * DD);   // 4096
  afm_kernel<<<B, 256, 0, stream>>>(feat, W, h, pvec, out);
}

// Round 3
// 101.436 us; speedup vs baseline: 2.1686x; 2.1686x over previous
//
#include <hip/hip_runtime.h>

// AFM: B=4096, F=50, D=16, A=32, P=1225 pairs.
// out[b] = sum_p softmax_p( relu(inter_p @ W) . h ) * (inter_p . p_vec)
// Round 3: MFMA formulation (Round 2 + compile fix: element-wise _Float16 casts
// instead of cvt_pkrtz, whose return type is __fp16-based and mismatched).
// Per 16-pair tile: D[a][p] = W^T[a][d] * inter^T[d][p] via
// mfma_f32_16x16x32_f16 (K zero-padded 16->32), pairs on N so the score
// reduction over a lands in (quad,reg) -> 2 shfl_xor per 16 pairs.
// g = inter . p_vec via a 3rd MFMA with A = [pvec; 0...] (row 0 only).

#define FF 50
#define DD 16
#define AA 32
#define NP 1225
#define NT 77        // ceil(NP/16)
#define EPAD 20      // e row stride in floats (80B, 16B-aligned, spreads banks)

typedef _Float16 half8 __attribute__((ext_vector_type(8)));
typedef float floatx4 __attribute__((ext_vector_type(4)));

__global__ __launch_bounds__(256) void afm_kernel(
    const float* __restrict__ feat,   // [B, 50, 16]
    const float* __restrict__ W,      // [16, 32]
    const float* __restrict__ h,      // [32]
    const float* __restrict__ pvec,   // [16]
    float* __restrict__ out)          // [B]
{
  __shared__ float e[FF * EPAD];            // 4000 B
  __shared__ unsigned short table[NT * 16]; // 1232 packed (i<<8)|j
  __shared__ float s_lds[NP];
  __shared__ float g_lds[NP];
  __shared__ float red[4];
  __shared__ float red2[4][2];

  const int tid  = threadIdx.x;
  const int b    = blockIdx.x;
  const int lane = tid & 63;
  const int wave = tid >> 6;
  const int quad = lane >> 4;
  const int col  = lane & 15;

  // ---- stage e with padded stride ----
  if (tid < 200) {
    const float4* src4 = (const float4*)(feat + (size_t)b * (FF * DD));
    int row = tid >> 2, q = tid & 3;
    *(float4*)(e + row * EPAD + q * 4) = src4[tid];
  }
  // ---- pair table ----
  if (tid < FF - 1) {
    int i = tid;
    int off = i * (FF - 1) - (i * (i - 1)) / 2;
    for (int n = 0; n < FF - 1 - i; ++n)
      table[off + n] = (unsigned short)((i << 8) | (i + 1 + n));
  }
  if (tid < NT * 16 - NP) table[NP + tid] = 0;  // pad pairs -> (0,0), writes masked

  // ---- loop-invariant A-fragments: A[m=lane&15][k=quad*8+j], k>=16 zero ----
  half8 A0 = (half8)(_Float16)0.f;  // W^T rows a=0..15
  half8 A1 = (half8)(_Float16)0.f;  // W^T rows a=16..31
  half8 A2 = (half8)(_Float16)0.f;  // row 0 = pvec (for g)
  if (quad < 2) {
    #pragma unroll
    for (int j = 0; j < 8; ++j) {
      int k = quad * 8 + j;
      A0[j] = (_Float16)W[k * AA + col];
      A1[j] = (_Float16)W[k * AA + col + 16];
    }
    if (col == 0) {
      #pragma unroll
      for (int j = 0; j < 8; ++j) A2[j] = (_Float16)pvec[quad * 8 + j];
    }
  }
  float h0[4], h1[4];
  #pragma unroll
  for (int r = 0; r < 4; ++r) {
    h0[r] = h[quad * 4 + r];
    h1[r] = h[16 + quad * 4 + r];
  }

  __syncthreads();

  // ---- phase 1: 16-pair tiles, one per wave round-robin ----
  for (int t = wave; t < NT; t += 4) {
    const int p = t * 16 + col;
    const int pk = table[p];
    half8 B = (half8)(_Float16)0.f;   // B[k=quad*8+j][n=lane&15], k>=16 zero
    if (quad < 2) {
      const int i = pk >> 8, j = pk & 255;
      const float4* ei = (const float4*)(e + i * EPAD + quad * 8);
      const float4* ej = (const float4*)(e + j * EPAD + quad * 8);
      float4 a0 = ei[0], a1 = ei[1];
      float4 b0 = ej[0], b1 = ej[1];
      B[0] = (_Float16)(a0.x * b0.x);
      B[1] = (_Float16)(a0.y * b0.y);
      B[2] = (_Float16)(a0.z * b0.z);
      B[3] = (_Float16)(a0.w * b0.w);
      B[4] = (_Float16)(a1.x * b1.x);
      B[5] = (_Float16)(a1.y * b1.y);
      B[6] = (_Float16)(a1.z * b1.z);
      B[7] = (_Float16)(a1.w * b1.w);
    }
    floatx4 z0 = {0.f, 0.f, 0.f, 0.f};
    floatx4 z1 = {0.f, 0.f, 0.f, 0.f};
    floatx4 zg = {0.f, 0.f, 0.f, 0.f};
    z0 = __builtin_amdgcn_mfma_f32_16x16x32_f16(A0, B, z0, 0, 0, 0);
    z1 = __builtin_amdgcn_mfma_f32_16x16x32_f16(A1, B, z1, 0, 0, 0);
    zg = __builtin_amdgcn_mfma_f32_16x16x32_f16(A2, B, zg, 0, 0, 0);

    float v = 0.f;
    #pragma unroll
    for (int r = 0; r < 4; ++r)
      v += fmaxf(z0[r], 0.f) * h0[r] + fmaxf(z1[r], 0.f) * h1[r];
    v += __shfl_xor(v, 16, 64);
    v += __shfl_xor(v, 32, 64);
    if (quad == 0 && p < NP) {
      s_lds[p] = v;
      g_lds[p] = zg[0];   // D[0][n]: row 0 lives in quad 0, reg 0
    }
  }
  __syncthreads();

  // ---- phase 2: softmax over 1225 + weighted g sum ----
  float m = -3.4e38f;
  for (int p = tid; p < NP; p += 256) m = fmaxf(m, s_lds[p]);
  #pragma unroll
  for (int s = 32; s >= 1; s >>= 1) m = fmaxf(m, __shfl_xor(m, s, 64));
  if ((tid & 63) == 0) red[wave] = m;
  __syncthreads();
  m = fmaxf(fmaxf(red[0], red[1]), fmaxf(red[2], red[3]));

  float num = 0.f, den = 0.f;
  for (int p = tid; p < NP; p += 256) {
    float ex = __expf(s_lds[p] - m);
    den += ex;
    num = fmaf(ex, g_lds[p], num);
  }
  #pragma unroll
  for (int s = 32; s >= 1; s >>= 1) {
    num += __shfl_xor(num, s, 64);
    den += __shfl_xor(den, s, 64);
  }
  if ((tid & 63) == 0) { red2[wave][0] = num; red2[wave][1] = den; }
  __syncthreads();
  if (tid == 0) {
    float n  = red2[0][0] + red2[1][0] + red2[2][0] + red2[3][0];
    float dd = red2[0][1] + red2[1][1] + red2[2][1] + red2[3][1];
    out[b] = n / dd;
  }
}

extern "C" void kernel_launch(void* const* d_in, const int* in_sizes, int n_in,
                              void* d_out, int out_size, void* d_ws, size_t ws_size,
                              hipStream_t stream) {
  const float* feat = (const float*)d_in[0];
  const float* W    = (const float*)d_in[1];
  const float* h    = (const float*)d_in[2];
  const float* pvec = (const float*)d_in[3];
  float* out = (float*)d_out;
  const int B = in_sizes[0] / (FF * DD);   // 4096
  afm_kernel<<<B, 256, 0, stream>>>(feat, W, h, pvec, out);
}

// Round 4
// 93.196 us; speedup vs baseline: 2.3603x; 1.0884x over previous
//
#include <hip/hip_runtime.h>
#include <math.h>

// AFM: B=4096, F=50, D=16, A=32, P=1225 pairs.
// out[b] = sum_p softmax_p( relu(inter_p @ W) . h ) * (inter_p . p_vec)
//
// Round 4: 32-pair tiles on mfma_f32_32x32x16_f16 (K=16 exact, no padding).
//  - e pre-converted to f16 in LDS (stride 24 halves = 48B, 16B-aligned).
//  - B fragment: 2x ds_read_b128 + 4x v_pk_mul_f16 (all 64 lanes active).
//  - z = W^T(32x16) . inter(16x32) in ONE MFMA; C/D: col=lane&31,
//    row a=(reg&3)+8*(reg>>2)+4*(lane>>5)  [verified m74/m101].
//  - g = inter . pvec via v_dot2_f32_f16 on the B fragment (no 2nd MFMA).
//  - Online softmax in registers: no s/g LDS arrays, no phase 2.

#define FF 50
#define DD 16
#define AA 32
#define NP 1225
#define NT32 39            // ceil(1225/32); padded to 1248 slots
#define ERS 24             // e row stride in halves (48 B, 16B-aligned)

typedef _Float16 half8 __attribute__((ext_vector_type(8)));
typedef _Float16 half4 __attribute__((ext_vector_type(4)));
typedef __fp16  fh2   __attribute__((ext_vector_type(2)));
typedef float floatx16 __attribute__((ext_vector_type(16)));

union H8U { half8 v; fh2 h2[4]; };

__global__ __launch_bounds__(256) void afm_kernel(
    const float* __restrict__ feat,   // [B, 50, 16]
    const float* __restrict__ W,      // [16, 32]
    const float* __restrict__ h,      // [32]
    const float* __restrict__ pvec,   // [16]
    float* __restrict__ out)          // [B]
{
  __shared__ __align__(16) _Float16 eh[FF * ERS];     // 2400 B
  __shared__ unsigned short table[NT32 * 32];         // 2496 B, (i<<8)|j
  __shared__ float wred[4][4];                        // per-wave (m,den,num)

  const int tid    = threadIdx.x;
  const int b      = blockIdx.x;
  const int lane   = tid & 63;
  const int wave   = tid >> 6;
  const int halfid = lane >> 5;      // 0/1: which K-half this lane feeds
  const int n      = lane & 31;      // pair column within tile

  // ---- stage e -> f16 LDS (200 float4 loads, convert, 8B writes) ----
  if (tid < 200) {
    const float4* src4 = (const float4*)(feat + (size_t)b * (FF * DD));
    float4 v4 = src4[tid];
    int row = tid >> 2, q = tid & 3;
    half4 hv;
    hv[0] = (_Float16)v4.x; hv[1] = (_Float16)v4.y;
    hv[2] = (_Float16)v4.z; hv[3] = (_Float16)v4.w;
    *(half4*)(&eh[row * ERS + q * 4]) = hv;
  }

  // ---- pair table, evenly spread: invert p -> (i,j) with sqrt + fixup ----
  for (int p = tid; p < NT32 * 32; p += 256) {
    unsigned short ent = 0;
    if (p < NP) {
      int rad = 9801 - 8 * p;                       // (99-2i)^2 at row starts
      int i = (int)((99.0f - sqrtf((float)rad)) * 0.5f);
      if (i < 0) i = 0; if (i > 48) i = 48;
      int off = (i * (99 - i)) >> 1;
      if (off > p) { --i; off = (i * (99 - i)) >> 1; }
      else {
        int off1 = ((i + 1) * (98 - i)) >> 1;
        if (off1 <= p) { ++i; off = off1; }
      }
      int j = p - off + i + 1;
      ent = (unsigned short)((i << 8) | j);
    }
    table[p] = ent;
  }

  // ---- loop-invariant fragments ----
  // A[m=lane&31][k=(lane>>5)*8+jj] = W^T[a][k] = W[k][a]
  half8 A0;
  #pragma unroll
  for (int jj = 0; jj < 8; ++jj)
    A0[jj] = (_Float16)W[(halfid * 8 + jj) * AA + n];
  // h for this lane's C-rows: a(r) = (r&3) + 8*(r>>2) + 4*halfid
  float hreg[16];
  #pragma unroll
  for (int r = 0; r < 16; ++r)
    hreg[r] = h[(r & 3) + 8 * (r >> 2) + 4 * halfid];
  // pvec (f16 pairs) for this lane's K-half
  fh2 pv2[4];
  #pragma unroll
  for (int q = 0; q < 4; ++q) {
    pv2[q][0] = (__fp16)pvec[halfid * 8 + 2 * q];
    pv2[q][1] = (__fp16)pvec[halfid * 8 + 2 * q + 1];
  }
  const floatx16 ZACC = (floatx16)0.0f;

  __syncthreads();

  // ---- phase 1: 32-pair tiles, online softmax in registers ----
  float m = -3.4e38f, den = 0.f, num = 0.f;
  for (int t = wave; t < NT32; t += 4) {
    const int p  = t * 32 + n;
    const int pk = table[p];
    const int i  = pk >> 8, j = pk & 255;
    H8U Bu;
    {
      half8 Bi = *(const half8*)(&eh[i * ERS + halfid * 8]);
      half8 Bj = *(const half8*)(&eh[j * ERS + halfid * 8]);
      Bu.v = Bi * Bj;     // 4x v_pk_mul_f16: inter in f16, B[k][n] layout
    }
    floatx16 z = __builtin_amdgcn_mfma_f32_32x32x16_f16(A0, Bu.v, ZACC, 0, 0, 0);

    float v = 0.f;
    #pragma unroll
    for (int r = 0; r < 16; ++r)
      v = fmaf(fmaxf(z[r], 0.f), hreg[r], v);
    v += __shfl_xor(v, 32, 64);          // both K-halves -> full score

    float g;
    {
      float gp = 0.f;
#if __has_builtin(__builtin_amdgcn_fdot2)
      #pragma unroll
      for (int q = 0; q < 4; ++q)
        gp = __builtin_amdgcn_fdot2(Bu.h2[q], pv2[q], gp, false);
#else
      #pragma unroll
      for (int q = 0; q < 4; ++q) {
        gp = fmaf((float)Bu.h2[q][0], (float)pv2[q][0], gp);
        gp = fmaf((float)Bu.h2[q][1], (float)pv2[q][1], gp);
      }
#endif
      g = gp + __shfl_xor(gp, 32, 64);   // sum both K-halves
    }

    if (p >= NP) v = -3.4e38f;           // pad pairs vanish in softmax
    float mn = fmaxf(m, v);
    float a1 = __expf(m - mn);
    float d1 = __expf(v - mn);
    den = fmaf(den, a1, d1);
    num = fmaf(num, a1, d1 * g);
    m = mn;
  }

  // ---- wave reduction: combine 32 online states (lanes duplicated x2) ----
  #pragma unroll
  for (int mask = 1; mask <= 16; mask <<= 1) {
    float mo = __shfl_xor(m, mask, 64);
    float dn = __shfl_xor(den, mask, 64);
    float no = __shfl_xor(num, mask, 64);
    float mn = fmaxf(m, mo);
    float a1 = __expf(m - mn), a2 = __expf(mo - mn);
    den = den * a1 + dn * a2;
    num = num * a1 + no * a2;
    m = mn;
  }
  if (lane == 0) { wred[wave][0] = m; wred[wave][1] = den; wred[wave][2] = num; }
  __syncthreads();

  if (tid == 0) {
    float M = -3.4e38f, D = 0.f, N = 0.f;
    #pragma unroll
    for (int w = 0; w < 4; ++w) {
      float wm = wred[w][0], wd = wred[w][1], wn = wred[w][2];
      float mn = fmaxf(M, wm);
      float a1 = __expf(M - mn), a2 = __expf(wm - mn);
      D = D * a1 + wd * a2;
      N = N * a1 + wn * a2;
      M = mn;
    }
    out[b] = N / D;
  }
}

extern "C" void kernel_launch(void* const* d_in, const int* in_sizes, int n_in,
                              void* d_out, int out_size, void* d_ws, size_t ws_size,
                              hipStream_t stream) {
  const float* feat = (const float*)d_in[0];
  const float* W    = (const float*)d_in[1];
  const float* h    = (const float*)d_in[2];
  const float* pvec = (const float*)d_in[3];
  float* out = (float*)d_out;
  const int B = in_sizes[0] / (FF * DD);   // 4096
  afm_kernel<<<B, 256, 0, stream>>>(feat, W, h, pvec, out);
}

// Round 5
// 91.416 us; speedup vs baseline: 2.4063x; 1.0195x over previous
//
#include <hip/hip_runtime.h>
#include <math.h>

// AFM: B=4096, F=50, D=16, A=32, P=1225 pairs.
// out[b] = sum_p softmax_p( relu(inter_p @ W) . h ) * (inter_p . p_vec)
//
// Round 5: one wave per batch element (4 batches/block, grid B/4).
//  - Prologue (pair table, e staging, W/h/pvec fragments) amortized over 4
//    batches; no cross-wave softmax combine, no epilogue syncthreads.
//  - Main loop: 2 tiles of 32 pairs per iteration on mfma_f32_32x32x16_f16
//    (K=16 exact). A[m=lane&31][k=(lane>>5)*8+jj], B[k][n=lane&31],
//    C/D row a=(reg&3)+8*(reg>>2)+4*(lane>>5)  [validated: R4 passed].
//  - g = inter . pvec via v_dot2_f32_f16 on the B fragment.
//  - Online softmax in log2 domain (exp2f = native v_exp_f32), fused update
//    for both tiles: 3 exp2 per 64 pairs.
//  - relu.h reduce with 4 accumulators (dep depth ~18 cyc vs 64).

#define FF 50
#define DD 16
#define AA 32
#define NP 1225
#define NT 40              // 32-pair tiles, padded to 1280 slots
#define ERS 24             // e row stride in halves (48 B, 16B-aligned)
#define EBS (FF * ERS)     // 1200 halves per batch element

typedef _Float16 half8 __attribute__((ext_vector_type(8)));
typedef _Float16 half4 __attribute__((ext_vector_type(4)));
typedef __fp16   fh2   __attribute__((ext_vector_type(2)));
typedef float    floatx16 __attribute__((ext_vector_type(16)));

union H8U { half8 v; fh2 h2[4]; };

__global__ __launch_bounds__(256, 4) void afm_kernel(
    const float* __restrict__ feat,   // [B, 50, 16]
    const float* __restrict__ W,      // [16, 32]
    const float* __restrict__ h,      // [32]
    const float* __restrict__ pvec,   // [16]
    float* __restrict__ out,          // [B]
    int Btot)
{
  __shared__ __align__(16) _Float16 eh[4 * EBS];   // 9600 B
  __shared__ unsigned short table[NT * 32];        // 2560 B, (i<<8)|j

  const int tid    = threadIdx.x;
  const int lane   = tid & 63;
  const int wave   = tid >> 6;
  const int halfid = lane >> 5;     // which K-half this lane feeds
  const int n      = lane & 31;     // pair column within tile
  const int b0     = blockIdx.x << 2;

  // ---- stage 4 batch elements -> f16 LDS ----
  for (int s = tid; s < 4 * 200; s += 256) {
    int bl  = s / 200;              // magic-mul
    int rem = s - bl * 200;
    int bb  = b0 + bl;
    if (bb < Btot) {
      float4 v4 = ((const float4*)feat)[(size_t)bb * 200 + rem];
      half4 hv;
      hv[0] = (_Float16)v4.x; hv[1] = (_Float16)v4.y;
      hv[2] = (_Float16)v4.z; hv[3] = (_Float16)v4.w;
      int row = rem >> 2, q = rem & 3;
      *(half4*)(&eh[bl * EBS + row * ERS + q * 4]) = hv;
    }
  }

  // ---- pair table: invert p -> (i,j) with sqrt + fixup ----
  for (int p = tid; p < NT * 32; p += 256) {
    unsigned short ent = 0;
    if (p < NP) {
      int rad = 9801 - 8 * p;
      int i = (int)((99.0f - sqrtf((float)rad)) * 0.5f);
      if (i < 0) i = 0; if (i > 48) i = 48;
      int off = (i * (99 - i)) >> 1;
      if (off > p) { --i; off = (i * (99 - i)) >> 1; }
      else {
        int off1 = ((i + 1) * (98 - i)) >> 1;
        if (off1 <= p) { ++i; off = off1; }
      }
      int j = p - off + i + 1;
      ent = (unsigned short)((i << 8) | j);
    }
    table[p] = ent;
  }

  // ---- loop-invariant fragments ----
  half8 A0;                                  // W^T in A-layout
  #pragma unroll
  for (int jj = 0; jj < 8; ++jj)
    A0[jj] = (_Float16)W[(halfid * 8 + jj) * AA + n];
  float hreg[16];                            // h at this lane's C-rows
  #pragma unroll
  for (int r = 0; r < 16; ++r)
    hreg[r] = h[(r & 3) + 8 * (r >> 2) + 4 * halfid];
  fh2 pv2[4];                                // pvec for this K-half
  #pragma unroll
  for (int q = 0; q < 4; ++q) {
    pv2[q][0] = (__fp16)pvec[halfid * 8 + 2 * q];
    pv2[q][1] = (__fp16)pvec[halfid * 8 + 2 * q + 1];
  }

  __syncthreads();

  // ---- main loop: this wave owns batch b0+wave entirely ----
  const _Float16* eb = &eh[wave * EBS];
  const float LOG2E = 1.4426950408889634f;
  float m = -3.0e38f, den = 0.f, num = 0.f;

  for (int t = 0; t < NT; t += 2) {
    float vl[2], gg[2];
    #pragma unroll
    for (int u = 0; u < 2; ++u) {
      const int p  = (t + u) * 32 + n;
      const int pk = table[p];
      const int i  = pk >> 8, j = pk & 255;
      H8U Bu;
      {
        half8 Bi = *(const half8*)(eb + i * ERS + halfid * 8);
        half8 Bj = *(const half8*)(eb + j * ERS + halfid * 8);
        Bu.v = Bi * Bj;                      // inter (f16), B[k][n] layout
      }
      floatx16 z = __builtin_amdgcn_mfma_f32_32x32x16_f16(
          A0, Bu.v, (floatx16)0.0f, 0, 0, 0);

      float a0 = 0.f, a1 = 0.f, a2 = 0.f, a3 = 0.f;
      #pragma unroll
      for (int r = 0; r < 16; r += 4) {
        a0 = fmaf(fmaxf(z[r + 0], 0.f), hreg[r + 0], a0);
        a1 = fmaf(fmaxf(z[r + 1], 0.f), hreg[r + 1], a1);
        a2 = fmaf(fmaxf(z[r + 2], 0.f), hreg[r + 2], a2);
        a3 = fmaf(fmaxf(z[r + 3], 0.f), hreg[r + 3], a3);
      }
      float v = (a0 + a1) + (a2 + a3);
      v += __shfl_xor(v, 32, 64);            // combine both K-halves

      float gp0, gp1;
#if __has_builtin(__builtin_amdgcn_fdot2)
      gp0 = __builtin_amdgcn_fdot2(Bu.h2[1], pv2[1],
            __builtin_amdgcn_fdot2(Bu.h2[0], pv2[0], 0.f, false), false);
      gp1 = __builtin_amdgcn_fdot2(Bu.h2[3], pv2[3],
            __builtin_amdgcn_fdot2(Bu.h2[2], pv2[2], 0.f, false), false);
#else
      gp0 = 0.f; gp1 = 0.f;
      #pragma unroll
      for (int q = 0; q < 2; ++q) {
        gp0 = fmaf((float)Bu.h2[q][0], (float)pv2[q][0], gp0);
        gp0 = fmaf((float)Bu.h2[q][1], (float)pv2[q][1], gp0);
        gp1 = fmaf((float)Bu.h2[q+2][0], (float)pv2[q+2][0], gp1);
        gp1 = fmaf((float)Bu.h2[q+2][1], (float)pv2[q+2][1], gp1);
      }
#endif
      float g = gp0 + gp1;
      g += __shfl_xor(g, 32, 64);

      vl[u] = (p < NP) ? v * LOG2E : -3.0e38f;
      gg[u] = g;
    }
    // fused online-softmax update (log2 domain): 3 exp2 per 64 pairs
    float mn = fmaxf(fmaxf(vl[0], vl[1]), m);
    float a  = exp2f(m - mn);
    float e0 = exp2f(vl[0] - mn);
    float e1 = exp2f(vl[1] - mn);
    den = fmaf(den, a, e0 + e1);
    num = fmaf(num, a, fmaf(e0, gg[0], e1 * gg[1]));
    m = mn;
  }

  // ---- combine 32 per-column states (lanes 0..31 / 32..63 are duplicates) ----
  #pragma unroll
  for (int mask = 16; mask >= 1; mask >>= 1) {
    float mo = __shfl_xor(m, mask, 64);
    float dn = __shfl_xor(den, mask, 64);
    float no = __shfl_xor(num, mask, 64);
    float mn = fmaxf(m, mo);
    float s1 = exp2f(m - mn), s2 = exp2f(mo - mn);
    den = den * s1 + dn * s2;
    num = num * s1 + no * s2;
    m = mn;
  }
  const int b = b0 + wave;
  if (lane == 0 && b < Btot) out[b] = num / den;
}

extern "C" void kernel_launch(void* const* d_in, const int* in_sizes, int n_in,
                              void* d_out, int out_size, void* d_ws, size_t ws_size,
                              hipStream_t stream) {
  const float* feat = (const float*)d_in[0];
  const float* W    = (const float*)d_in[1];
  const float* h    = (const float*)d_in[2];
  const float* pvec = (const float*)d_in[3];
  float* out = (float*)d_out;
  const int B = in_sizes[0] / (FF * DD);   // 4096
  afm_kernel<<<(B + 3) / 4, 256, 0, stream>>>(feat, W, h, pvec, out, B);
}

// Round 6
// 90.680 us; speedup vs baseline: 2.4258x; 1.0081x over previous
//
#include <hip/hip_runtime.h>
#include <math.h>

// AFM: B=4096, F=50, D=16, A=32, P=1225 pairs.
// out[b] = sum_p softmax_p( relu(inter_p @ W) . h ) * (inter_p . p_vec)
//
// Round 6: R5 structure minus all union type-punning (suspected scratch
// alloca => ~2000 cyc/tile). One wave per batch element (4 per block).
//  - 32-pair tiles on mfma_f32_32x32x16_f16 (K=16 exact). Layouts validated
//    R4/R5: A[m=lane&31][k=(lane>>5)*8+jj], B[k][n=lane&31],
//    C/D row a=(reg&3)+8*(reg>>2)+4*(lane>>5).
//  - g = inter . pvec via fmaf((float)f16, f32, f32) -> v_fma_mix_f32.
//  - g half-combine deferred to the final butterfly (mask-32 step); per-tile
//    g-shfl deleted. out = 2*num/den compensates den double-count.
//  - Table holds pre-scaled LDS byte offsets (i*48)<<16 | (j*48).
//  - h pre-scaled by log2(e): online softmax fully in exp2 domain.
//  - Tiles 0..37 maskless; tile 38 (9 valid pairs) peeled with mask.

#define FF 50
#define DD 16
#define AA 32
#define NP 1225
#define NT 39              // 32-pair tiles; tile 38 partial (pairs 1216..1224)
#define ERS 24             // halves per e-row (48 B, 16B-aligned)
#define EBS (FF * ERS)     // 1200 halves per batch element

typedef _Float16 half8 __attribute__((ext_vector_type(8)));
typedef _Float16 half4 __attribute__((ext_vector_type(4)));
typedef float    floatx16 __attribute__((ext_vector_type(16)));

__global__ __launch_bounds__(256, 4) void afm_kernel(
    const float* __restrict__ feat,   // [B, 50, 16]
    const float* __restrict__ W,      // [16, 32]
    const float* __restrict__ h,      // [32]
    const float* __restrict__ pvec,   // [16]
    float* __restrict__ out,          // [B]
    int Btot)
{
  __shared__ __align__(16) _Float16 eh[4 * EBS];   // 9600 B
  __shared__ unsigned int tbl[NT * 32];            // 4992 B byte-offset pairs

  const int tid    = threadIdx.x;
  const int lane   = tid & 63;
  const int wave   = tid >> 6;
  const int halfid = lane >> 5;      // which K-half this lane feeds
  const int n      = lane & 31;      // pair column within tile
  const int b0     = blockIdx.x << 2;
  const int b      = b0 + wave;

  // ---- stage 4 batch elements -> f16 LDS ----
  for (int s = tid; s < 4 * 200; s += 256) {
    int bl  = s / 200;
    int rem = s - bl * 200;
    int bb  = b0 + bl;
    if (bb < Btot) {
      float4 v4 = ((const float4*)feat)[(size_t)bb * 200 + rem];
      half4 hv;
      hv[0] = (_Float16)v4.x; hv[1] = (_Float16)v4.y;
      hv[2] = (_Float16)v4.z; hv[3] = (_Float16)v4.w;
      int row = rem >> 2, q = rem & 3;
      *(half4*)(&eh[bl * EBS + row * ERS + q * 4]) = hv;
    }
  }

  // ---- pair table: p -> packed byte offsets (i*48)<<16 | (j*48) ----
  for (int p = tid; p < NT * 32; p += 256) {
    unsigned ent = 0;                              // pad -> row0,row0 (masked)
    if (p < NP) {
      int rad = 9801 - 8 * p;
      int i = (int)((99.0f - sqrtf((float)rad)) * 0.5f);
      if (i < 0) i = 0; if (i > 48) i = 48;
      int off = (i * (99 - i)) >> 1;
      if (off > p) { --i; off = (i * (99 - i)) >> 1; }
      else {
        int off1 = ((i + 1) * (98 - i)) >> 1;
        if (off1 <= p) { ++i; off = off1; }
      }
      int j = p - off + i + 1;
      ent = ((unsigned)(i * 48) << 16) | (unsigned)(j * 48);
    }
    tbl[p] = ent;
  }

  // ---- loop-invariant fragments ----
  const float LOG2E = 1.4426950408889634f;
  half8 A0;                                  // W^T in A-layout
  #pragma unroll
  for (int jj = 0; jj < 8; ++jj)
    A0[jj] = (_Float16)W[(halfid * 8 + jj) * AA + n];
  float hreg[16];                            // h at this lane's C-rows, *log2e
  #pragma unroll
  for (int r = 0; r < 16; ++r)
    hreg[r] = h[(r & 3) + 8 * (r >> 2) + 4 * halfid] * LOG2E;
  float pvf[8];                              // pvec slice for this K-half (f32)
  #pragma unroll
  for (int k = 0; k < 8; ++k) pvf[k] = pvec[halfid * 8 + k];

  __syncthreads();

  // ---- main loop: this wave owns batch b entirely ----
  const char* ebase = (const char*)(eh + wave * EBS) + halfid * 16;

  auto tile = [&](int t, float& vout, float& gout) {
    unsigned ij = tbl[t * 32 + n];
    half8 Bi = *(const half8*)(ebase + (ij >> 16));
    half8 Bj = *(const half8*)(ebase + (ij & 0xffffu));
    half8 Bv = Bi * Bj;                      // inter (f16), B[k][n] layout
    floatx16 z = __builtin_amdgcn_mfma_f32_32x32x16_f16(
        A0, Bv, (floatx16)0.0f, 0, 0, 0);
    float a0 = 0.f, a1 = 0.f, a2 = 0.f, a3 = 0.f;
    #pragma unroll
    for (int r = 0; r < 16; r += 4) {
      a0 = fmaf(fmaxf(z[r + 0], 0.f), hreg[r + 0], a0);
      a1 = fmaf(fmaxf(z[r + 1], 0.f), hreg[r + 1], a1);
      a2 = fmaf(fmaxf(z[r + 2], 0.f), hreg[r + 2], a2);
      a3 = fmaf(fmaxf(z[r + 3], 0.f), hreg[r + 3], a3);
    }
    float v = (a0 + a1) + (a2 + a3);
    v += __shfl_xor(v, 32, 64);              // combine K-halves (log2 domain)
    float g = 0.f;                           // THIS half's partial only
    #pragma unroll
    for (int k = 0; k < 8; ++k)
      g = fmaf((float)Bv[k], pvf[k], g);     // v_fma_mix_f32
    vout = v; gout = g;
  };

  float m = -3.0e38f, den = 0.f, num = 0.f;

  for (int t = 0; t < 38; t += 2) {          // tiles 0..37, all pairs valid
    float v0, g0, v1, g1;
    tile(t, v0, g0);
    tile(t + 1, v1, g1);
    float mn = fmaxf(fmaxf(v0, v1), m);
    float a  = exp2f(m - mn);
    float e0 = exp2f(v0 - mn);
    float e1 = exp2f(v1 - mn);
    den = fmaf(den, a, e0 + e1);
    num = fmaf(num, a, fmaf(e0, g0, e1 * g1));
    m = mn;
  }
  {                                          // peeled tile 38: valid n < 9
    float v, g;
    tile(38, v, g);
    float vl = (1216 + n < NP) ? v : -3.0e38f;
    float mn = fmaxf(m, vl);
    float a  = exp2f(m - mn);
    float e0 = exp2f(vl - mn);
    den = fmaf(den, a, e0);
    num = fmaf(num, a, e0 * g);
    m = mn;
  }

  // ---- butterfly over all 64 lanes (mask-32 merges the g-halves) ----
  #pragma unroll
  for (int mask = 32; mask >= 1; mask >>= 1) {
    float mo = __shfl_xor(m, mask, 64);
    float dn = __shfl_xor(den, mask, 64);
    float no = __shfl_xor(num, mask, 64);
    float mn = fmaxf(m, mo);
    float s1 = exp2f(m - mn), s2 = exp2f(mo - mn);
    den = den * s1 + dn * s2;
    num = num * s1 + no * s2;
    m = mn;
  }
  // den counts every pair twice (both K-half lanes); num exactly once.
  if (lane == 0 && b < Btot) out[b] = (2.0f * num) / den;
}

extern "C" void kernel_launch(void* const* d_in, const int* in_sizes, int n_in,
                              void* d_out, int out_size, void* d_ws, size_t ws_size,
                              hipStream_t stream) {
  const float* feat = (const float*)d_in[0];
  const float* W    = (const float*)d_in[1];
  const float* h    = (const float*)d_in[2];
  const float* pvec = (const float*)d_in[3];
  float* out = (float*)d_out;
  const int B = in_sizes[0] / (FF * DD);   // 4096
  afm_kernel<<<(B + 3) / 4, 256, 0, stream>>>(feat, W, h, pvec, out, B);
}

// Round 7
// 89.862 us; speedup vs baseline: 2.4479x; 1.0091x over previous
//
#include <hip/hip_runtime.h>
#include <math.h>

// AFM: B=4096, F=50, D=16, A=32, P=1225 pairs.
// out[b] = sum_p softmax_p( relu(inter_p @ W) . h ) * (inter_p . p_vec)
//
// Round 7: one wave owns TWO batch elements (8/block, grid B/8).
//  - Dual independent tile-chains per wave (ILP x2); table entry + decode
//    shared between the two batches (identical pair schedule).
//  - No-max softmax: scores bounded (|log2 s| << 128) -> den += 2^v,
//    num += 2^v * g. No rescale chain; final butterfly is pure adds.
//  - Table stored interleaved as uint2[(t/2)*32+n] = {ent(t,n), ent(t+1,n)}
//    -> one ds_read_b64 per 2 tiles. Entries are LDS byte offsets
//    (i*48)<<16 | (j*48).
//  - g-dot in packed f16; score reduce kept in f32 (exp-sensitive).
//  - MFMA mfma_f32_32x32x16_f16, layouts validated R4-R6:
//    A[m=lane&31][k=(lane>>5)*8+jj], B[k][n=lane&31],
//    C/D row a=(reg&3)+8*(reg>>2)+4*(lane>>5), col n=lane&31.

#define FF 50
#define DD 16
#define AA 32
#define NP 1225
#define NT 39              // tiles of 32 pairs; tile 38 partial (9 valid)
#define NTP 40             // padded to even for uint2 interleave
#define ERS 24             // halves per e-row (48 B)
#define EBS (FF * ERS)     // 1200 halves per batch element

typedef _Float16 half8 __attribute__((ext_vector_type(8)));
typedef _Float16 half4 __attribute__((ext_vector_type(4)));
typedef _Float16 half2v __attribute__((ext_vector_type(2)));
typedef float    floatx16 __attribute__((ext_vector_type(16)));

__global__ __launch_bounds__(256, 4) void afm_kernel(
    const float* __restrict__ feat,   // [B, 50, 16]
    const float* __restrict__ W,      // [16, 32]
    const float* __restrict__ h,      // [32]
    const float* __restrict__ pvec,   // [16]
    float* __restrict__ out,          // [B]
    int Btot)
{
  __shared__ __align__(16) _Float16 eh[8 * EBS];   // 19200 B
  __shared__ unsigned int tbl[NTP * 32];           // 5120 B, interleaved pairs

  const int tid    = threadIdx.x;
  const int lane   = tid & 63;
  const int wave   = tid >> 6;
  const int halfid = lane >> 5;
  const int n      = lane & 31;
  const int b0     = blockIdx.x << 3;

  // ---- stage 8 batch elements -> f16 LDS ----
  for (int s = tid; s < 8 * 200; s += 256) {
    int bl  = s / 200;
    int rem = s - bl * 200;
    int bb  = b0 + bl;
    if (bb < Btot) {
      float4 v4 = ((const float4*)feat)[(size_t)bb * 200 + rem];
      half4 hv;
      hv[0] = (_Float16)v4.x; hv[1] = (_Float16)v4.y;
      hv[2] = (_Float16)v4.z; hv[3] = (_Float16)v4.w;
      int row = rem >> 2, q = rem & 3;
      *(half4*)(&eh[bl * EBS + row * ERS + q * 4]) = hv;
    }
  }

  // ---- interleaved pair table: dword q holds ent(t,n), t=2*(q>>6)+(q&1),
  //      n=(q>>1)&31; ent = (i*48)<<16 | (j*48), 0 for pads ----
  for (int q = tid; q < NTP * 32; q += 256) {
    int t = ((q >> 6) << 1) | (q & 1);
    int nn = (q >> 1) & 31;
    int p = t * 32 + nn;
    unsigned ent = 0;
    if (p < NP) {
      int rad = 9801 - 8 * p;
      int i = (int)((99.0f - sqrtf((float)rad)) * 0.5f);
      if (i < 0) i = 0; if (i > 48) i = 48;
      int off = (i * (99 - i)) >> 1;
      if (off > p) { --i; off = (i * (99 - i)) >> 1; }
      else {
        int off1 = ((i + 1) * (98 - i)) >> 1;
        if (off1 <= p) { ++i; off = off1; }
      }
      int j = p - off + i + 1;
      ent = ((unsigned)(i * 48) << 16) | (unsigned)(j * 48);
    }
    tbl[q] = ent;
  }

  // ---- loop-invariant fragments ----
  const float LOG2E = 1.4426950408889634f;
  half8 A0;
  #pragma unroll
  for (int jj = 0; jj < 8; ++jj)
    A0[jj] = (_Float16)W[(halfid * 8 + jj) * AA + n];
  float hreg[16];
  #pragma unroll
  for (int r = 0; r < 16; ++r)
    hreg[r] = h[(r & 3) + 8 * (r >> 2) + 4 * halfid] * LOG2E;
  half8 PV;                                   // pvec slice (f16) for this half
  #pragma unroll
  for (int k = 0; k < 8; ++k) PV[k] = (_Float16)pvec[halfid * 8 + k];

  __syncthreads();

  // ---- main loop: this wave owns batches bA = b0+2*wave, bB = bA+1 ----
  const char* ebA = (const char*)(eh + (2 * wave) * EBS) + halfid * 16;
  const char* ebB = ebA + EBS * sizeof(_Float16);

  // per-tile core for one batch, given byte offsets oi, oj
  auto core = [&](const char* eb, unsigned oi, unsigned oj,
                  float& vout, float& gout) {
    half8 Bi = *(const half8*)(eb + oi);
    half8 Bj = *(const half8*)(eb + oj);
    half8 Bv = Bi * Bj;                       // 4x v_pk_mul_f16
    floatx16 z = __builtin_amdgcn_mfma_f32_32x32x16_f16(
        A0, Bv, (floatx16)0.0f, 0, 0, 0);
    float a0 = 0.f, a1 = 0.f, a2 = 0.f, a3 = 0.f;
    #pragma unroll
    for (int r = 0; r < 16; r += 4) {
      a0 = fmaf(fmaxf(z[r + 0], 0.f), hreg[r + 0], a0);
      a1 = fmaf(fmaxf(z[r + 1], 0.f), hreg[r + 1], a1);
      a2 = fmaf(fmaxf(z[r + 2], 0.f), hreg[r + 2], a2);
      a3 = fmaf(fmaxf(z[r + 3], 0.f), hreg[r + 3], a3);
    }
    float v = (a0 + a1) + (a2 + a3);
    vout = v + __shfl_xor(v, 32, 64);         // combine K-halves (log2 domain)
    // g partial (this K-half) in packed f16
    half8 gp = Bv * PV;                       // 4x v_pk_mul_f16
    half4 g4 = {(_Float16)(gp[0] + gp[4]), (_Float16)(gp[1] + gp[5]),
                (_Float16)(gp[2] + gp[6]), (_Float16)(gp[3] + gp[7])};
    half2v g2 = {(_Float16)(g4[0] + g4[2]), (_Float16)(g4[1] + g4[3])};
    gout = (float)g2[0] + (float)g2[1];
  };

  float denA = 0.f, numA = 0.f, denB = 0.f, numB = 0.f;

  const unsigned int* tpair = tbl + 2 * n;    // this lane's interleaved column
  for (int th = 0; th < 19; ++th) {           // tiles 0..37, all valid
    uint2 ij2 = *(const uint2*)(tpair + th * 64);
    unsigned oi0 = ij2.x >> 16, oj0 = ij2.x & 0xffffu;
    unsigned oi1 = ij2.y >> 16, oj1 = ij2.y & 0xffffu;
    float v, g;
    core(ebA, oi0, oj0, v, g);
    { float e = exp2f(v); denA += e; numA = fmaf(e, g, numA); }
    core(ebB, oi0, oj0, v, g);
    { float e = exp2f(v); denB += e; numB = fmaf(e, g, numB); }
    core(ebA, oi1, oj1, v, g);
    { float e = exp2f(v); denA += e; numA = fmaf(e, g, numA); }
    core(ebB, oi1, oj1, v, g);
    { float e = exp2f(v); denB += e; numB = fmaf(e, g, numB); }
  }
  {                                           // peeled tile 38: valid n < 9
    unsigned ij = tpair[19 * 64];
    unsigned oi = ij >> 16, oj = ij & 0xffffu;
    float v, g;
    core(ebA, oi, oj, v, g);
    if (n >= 9) v = -3.0e38f;
    { float e = exp2f(v); denA += e; numA = fmaf(e, g, numA); }
    core(ebB, oi, oj, v, g);
    if (n >= 9) v = -3.0e38f;
    { float e = exp2f(v); denB += e; numB = fmaf(e, g, numB); }
  }

  // ---- butterfly: pure adds (mask-32 merges g-halves; den double-counts) ----
  #pragma unroll
  for (int mask = 32; mask >= 1; mask >>= 1) {
    denA += __shfl_xor(denA, mask, 64);
    numA += __shfl_xor(numA, mask, 64);
    denB += __shfl_xor(denB, mask, 64);
    numB += __shfl_xor(numB, mask, 64);
  }
  const int bA = b0 + 2 * wave;
  if (lane == 0 && bA < Btot)     out[bA]     = (2.0f * numA) / denA;
  if (lane == 0 && bA + 1 < Btot) out[bA + 1] = (2.0f * numB) / denB;
}

extern "C" void kernel_launch(void* const* d_in, const int* in_sizes, int n_in,
                              void* d_out, int out_size, void* d_ws, size_t ws_size,
                              hipStream_t stream) {
  const float* feat = (const float*)d_in[0];
  const float* W    = (const float*)d_in[1];
  const float* h    = (const float*)d_in[2];
  const float* pvec = (const float*)d_in[3];
  float* out = (float*)d_out;
  const int B = in_sizes[0] / (FF * DD);   // 4096
  afm_kernel<<<(B + 7) / 8, 256, 0, stream>>>(feat, W, h, pvec, out, B);
}